// Round 9
// baseline (2720.958 us; speedup 1.0000x reference)
//
#include <hip/hip_runtime.h>
#include <math.h>

#define BB 64
#define NN 256
#define MM 256
#define EPSF 1e-7f
#define ROWS_LDS 156   // 156 KB row cache + jofrow/matches/u0 ~3 KB = 159 KB <= 160 KB

// ---------- helpers ----------

__device__ __forceinline__ void iou_diou(const float4 pb, const float4 tb,
                                         float& iou, float& diou) {
    float x1 = pb.x - pb.z * 0.5f, y1 = pb.y - pb.w * 0.5f;
    float x2 = pb.x + pb.z * 0.5f, y2 = pb.y + pb.w * 0.5f;
    float xg1 = tb.x - tb.z * 0.5f, yg1 = tb.y - tb.w * 0.5f;
    float xg2 = tb.x + tb.z * 0.5f, yg2 = tb.y + tb.w * 0.5f;
    float xi1 = fmaxf(x1, xg1), yi1 = fmaxf(y1, yg1);
    float xi2 = fminf(x2, xg2), yi2 = fminf(y2, yg2);
    float inter = fmaxf(xi2 - xi1, 0.f) * fmaxf(yi2 - yi1, 0.f);
    float uni = (x2 - x1) * (y2 - y1) + (xg2 - xg1) * (yg2 - yg1) - inter;
    iou = inter / uni;
    float iou_e = inter / (uni + EPSF);
    float xc1 = fminf(x1, xg1), yc1 = fminf(y1, yg1);
    float xc2 = fmaxf(x2, xg2), yc2 = fmaxf(y2, yg2);
    float dx = xc2 - xc1, dy = yc2 - yc1;
    float diag = dx * dx + dy * dy + EPSF;
    float ex = (x1 + x2 - xg1 - xg2) * 0.5f;
    float ey = (y1 + y2 - yg1 - yg2) * 0.5f;
    float dist = ex * ex + ey * ey;
    diou = 1.f - iou_e + dist / diag;
}

// monotone double -> u64 key, low 9 bits replaced by column index (1..256).
__device__ __forceinline__ unsigned long long dkey(double d, int j) {
    unsigned long long b = (unsigned long long)__double_as_longlong(d);
    b ^= (b >> 63) ? 0xFFFFFFFFFFFFFFFFULL : 0x8000000000000000ULL;
    return (b & ~511ULL) | (unsigned long long)j;
}
__device__ __forceinline__ double unkey(unsigned long long k) {
    unsigned long long b = k & ~511ULL;
    b ^= (b & 0x8000000000000000ULL) ? 0x8000000000000000ULL : 0xFFFFFFFFFFFFFFFFULL;
    return __longlong_as_double((long long)b);
}

#define SEL4I(s, a0, a1, a2, a3) ((s) == 0 ? (a0) : (s) == 1 ? (a1) : (s) == 2 ? (a2) : (a3))
#define SEL4D(s, a0, a1, a2, a3) ((s) == 0 ? (a0) : (s) == 1 ? (a1) : (s) == 2 ? (a2) : (a3))

// uniform-lane readlane of a double held in a VGPR pair
__device__ __forceinline__ double readlane_d(double v, int lane) {
    unsigned long long b = (unsigned long long)__double_as_longlong(v);
    int lo = __builtin_amdgcn_readlane((int)(unsigned int)b, lane);
    int hi = __builtin_amdgcn_readlane((int)(unsigned int)(b >> 32), lane);
    return __longlong_as_double((long long)(((unsigned long long)(unsigned int)hi << 32) |
                                            (unsigned long long)(unsigned int)lo));
}

// Directional DPP min-reduce step, KEY ONLY (u64). old=self, bound_ctrl=false.
#define RED_DPP_K(CTRL)                                                                     \
    do {                                                                                    \
        int lo_ = (int)(unsigned int)ka, hi_ = (int)(unsigned int)(ka >> 32);               \
        int nlo_ = __builtin_amdgcn_update_dpp(lo_, lo_, CTRL, 0xF, 0xF, false);            \
        int nhi_ = __builtin_amdgcn_update_dpp(hi_, hi_, CTRL, 0xF, 0xF, false);            \
        unsigned long long ok_ = ((unsigned long long)(unsigned int)nhi_ << 32) |           \
                                 (unsigned long long)(unsigned int)nlo_;                    \
        if (ok_ < ka) ka = ok_;                                                             \
    } while (0)

// payload variant: carries pa_l (i32) alongside the key
#define RED_DPP_P(CTRL)                                                                     \
    do {                                                                                    \
        int lo_ = (int)(unsigned int)ka, hi_ = (int)(unsigned int)(ka >> 32);               \
        int nlo_ = __builtin_amdgcn_update_dpp(lo_, lo_, CTRL, 0xF, 0xF, false);            \
        int nhi_ = __builtin_amdgcn_update_dpp(hi_, hi_, CTRL, 0xF, 0xF, false);            \
        int npa_ = __builtin_amdgcn_update_dpp(pa_l, pa_l, CTRL, 0xF, 0xF, false);          \
        unsigned long long ok_ = ((unsigned long long)(unsigned int)nhi_ << 32) |           \
                                 (unsigned long long)(unsigned int)nlo_;                    \
        if (ok_ < ka) { ka = ok_; pa_l = npa_; }                                            \
    } while (0)

#define RED_ALL()                                                                           \
    do {                                                                                    \
        RED_DPP_K(0x111); RED_DPP_K(0x112); RED_DPP_K(0x114); RED_DPP_K(0x118);             \
        RED_DPP_K(0x142); RED_DPP_K(0x143);                                                 \
        unsigned int klo_ = (unsigned int)__builtin_amdgcn_readlane((int)(unsigned int)ka, 63); \
        unsigned int khi_ = (unsigned int)__builtin_amdgcn_readlane((int)(unsigned int)(ka >> 32), 63); \
        ka = ((unsigned long long)khi_ << 32) | klo_;                                       \
    } while (0)

// u32 min reduce (for nonneg f32 bits — monotone). Result broadcast from lane 63.
#define RED_U32_STEP(CTRL)                                                                  \
    do {                                                                                    \
        unsigned int n_ = (unsigned int)__builtin_amdgcn_update_dpp((int)kb, (int)kb, CTRL, 0xF, 0xF, false); \
        if (n_ < kb) kb = n_;                                                               \
    } while (0)
#define RED_U32_ALL()                                                                       \
    do {                                                                                    \
        RED_U32_STEP(0x111); RED_U32_STEP(0x112); RED_U32_STEP(0x114); RED_U32_STEP(0x118); \
        RED_U32_STEP(0x142); RED_U32_STEP(0x143);                                           \
        kb = (unsigned int)__builtin_amdgcn_readlane((int)kb, 63);                          \
    } while (0)

// ---------- K0: per-(b,n) BCE log terms ----------
__global__ __launch_bounds__(256) void k_prep(const float* __restrict__ lp,
                                              float* __restrict__ A,
                                              float* __restrict__ C) {
    int idx = blockIdx.x * 256 + threadIdx.x;
    float x = lp[idx];
    float p = 1.f / (1.f + expf(-x));
    A[idx] = -fmaxf(logf(p), -100.f);
    C[idx] = -fmaxf(logf(1.f - p), -100.f);
}

// ---------- K1: batch-constant label_cost and l1_cost [N,M] ----------
__global__ __launch_bounds__(256) void k_nm(const float* __restrict__ A,
                                            const float* __restrict__ C,
                                            const float* __restrict__ bp,
                                            const float* __restrict__ bt,
                                            const float* __restrict__ lt,
                                            float* __restrict__ lc,
                                            float* __restrict__ l1c) {
    int n = blockIdx.x, m = threadIdx.x;
    float sl = 0.f, s1 = 0.f;
    for (int b = 0; b < BB; ++b) {
        float a = A[b * NN + n];
        float c = C[b * NN + n];
        float t = lt[b * MM + m];
        sl += t * a + (1.f - t) * c;
        float4 P = *reinterpret_cast<const float4*>(bp + ((size_t)b * NN + n) * 4);
        float4 T = *reinterpret_cast<const float4*>(bt + ((size_t)b * MM + m) * 4);
        s1 += fabsf(P.x - T.x) + fabsf(P.y - T.y) + fabsf(P.z - T.z) + fabsf(P.w - T.w);
    }
    lc[n * MM + m]  = sl * (1.f / 64.f);
    l1c[n * MM + m] = s1 * (1.f / 256.f);
}

// ---------- K2: full cost tensor [B,N,M] ----------
__global__ __launch_bounds__(256) void k_cost(const float* __restrict__ bp,
                                              const float* __restrict__ bt,
                                              const float* __restrict__ lc,
                                              const float* __restrict__ l1c,
                                              float* __restrict__ cost) {
    int bn = blockIdx.x;
    int b = bn >> 8, n = bn & 255;
    int m = threadIdx.x;
    float4 P = *reinterpret_cast<const float4*>(bp + ((size_t)bn) * 4);
    float4 T = *reinterpret_cast<const float4*>(bt + ((size_t)b * MM + m) * 4);
    float iou, diou;
    iou_diou(P, T, iou, diou);
    cost[((size_t)bn << 8) + m] = diou + lc[(n << 8) + m] + l1c[(n << 8) + m];
}

// ---------- K3: exact LAP (rowred + colred + RT + greedy2 + SSP), 1 wave/batch --
__global__ __launch_bounds__(64) void k_hungarian(const float* __restrict__ cost,
                                                  int* __restrict__ cols) {
    const int b = blockIdx.x;
    const int lane = threadIdx.x;
    const float* Cm = cost + (size_t)b * NN * MM;
    const unsigned long long MAXK = 0xFFFFFFFFFFFFFFFFULL;
    const double INFD = __builtin_inf();

    __shared__ float ldsC[ROWS_LDS * MM];
    __shared__ float ldsU[NN];       // row duals u0[i] (exact f32 row minima)
    __shared__ int jofrow[NN + 1];   // smallest column (1-based) whose argmin is this row
    __shared__ int matches[NN + 1];  // # columns whose argmin is this row
    for (int r = lane; r <= NN; r += 64) { jofrow[r] = 0x7fffffff; matches[r] = 0; }
    __syncthreads();

    // uniform-row load: LDS-resident if cached, else global (L2)
    #define LOAD_ROW(r) ((r) - 1 < ROWS_LDS                                                  \
        ? *reinterpret_cast<const float4*>(&ldsC[((r) - 1) * MM + 4 * lane])                 \
        : *reinterpret_cast<const float4*>(Cm + (size_t)((r) - 1) * MM + 4 * lane))

    // ---- fused row reduction + column reduction on (c - u0) + LDS stash ----
    double cm0 = INFD, cm1 = INFD, cm2 = INFD, cm3 = INFD;
    int rm0 = 0, rm1 = 0, rm2 = 0, rm3 = 0;
    for (int i = 0; i < NN; ++i) {
        float4 cr = *reinterpret_cast<const float4*>(Cm + (size_t)i * MM + 4 * lane);
        if (i < ROWS_LDS) *reinterpret_cast<float4*>(&ldsC[i * MM + 4 * lane]) = cr;
        float rl = fminf(fminf(cr.x, cr.y), fminf(cr.z, cr.w));
        unsigned int kb = __float_as_uint(rl);
        RED_U32_ALL();
        float u0i = __uint_as_float(kb);
        if (lane == 0) ldsU[i] = u0i;
        double du = (double)u0i;
        double h0 = (double)cr.x - du;
        double h1 = (double)cr.y - du;
        double h2 = (double)cr.z - du;
        double h3 = (double)cr.w - du;
        if (h0 < cm0) { cm0 = h0; rm0 = i; }
        if (h1 < cm1) { cm1 = h1; rm1 = i; }
        if (h2 < cm2) { cm2 = h2; rm2 = i; }
        if (h3 < cm3) { cm3 = h3; rm3 = i; }
    }
    atomicMin(&jofrow[rm0 + 1], 4 * lane + 1);
    atomicMin(&jofrow[rm1 + 1], 4 * lane + 2);
    atomicMin(&jofrow[rm2 + 1], 4 * lane + 3);
    atomicMin(&jofrow[rm3 + 1], 4 * lane + 4);
    atomicAdd(&matches[rm0 + 1], 1);
    atomicAdd(&matches[rm1 + 1], 1);
    atomicAdd(&matches[rm2 + 1], 1);
    atomicAdd(&matches[rm3 + 1], 1);
    __syncthreads();

    // ---- greedy pre-assignment + register state init ----
    double vj0 = cm0, vj1 = cm1, vj2 = cm2, vj3 = cm3;   // v[j]
    int pj0_ = (jofrow[rm0 + 1] == 4 * lane + 1) ? rm0 + 1 : 0;
    int pj1_ = (jofrow[rm1 + 1] == 4 * lane + 2) ? rm1 + 1 : 0;
    int pj2_ = (jofrow[rm2 + 1] == 4 * lane + 3) ? rm2 + 1 : 0;
    int pj3_ = (jofrow[rm3 + 1] == 4 * lane + 4) ? rm3 + 1 : 0;
    double up0 = pj0_ ? (double)ldsU[pj0_ - 1] : 0.0;
    double up1 = pj1_ ? (double)ldsU[pj1_ - 1] : 0.0;
    double up2 = pj2_ ? (double)ldsU[pj2_ - 1] : 0.0;
    double up3 = pj3_ ? (double)ldsU[pj3_ - 1] : 0.0;
    int wy0 = 0, wy1 = 0, wy2 = 0, wy3 = 0;              // way[j]

    unsigned long long am0 = __ballot(jofrow[1 + lane]       != 0x7fffffff);
    unsigned long long am1 = __ballot(jofrow[1 + 64 + lane]  != 0x7fffffff);
    unsigned long long am2 = __ballot(jofrow[1 + 128 + lane] != 0x7fffffff);
    unsigned long long am3 = __ballot(jofrow[1 + 192 + lane] != 0x7fffffff);

    // ================= REDUCTION TRANSFER (rows claimed exactly once) =========
    for (int i = 1; i <= NN; ++i) {
        if (matches[i] != 1) continue;               // uniform branch
        int j1 = jofrow[i];                          // uniform
        int o = (j1 - 1) >> 2, s = (j1 - 1) & 3;
        float4 cr = LOAD_ROW(i);
        double du = (double)ldsU[i - 1];
        double h0 = ((double)cr.x - du) - vj0;
        double h1 = ((double)cr.y - du) - vj1;
        double h2 = ((double)cr.z - du) - vj2;
        double h3 = ((double)cr.w - du) - vj3;
        if (lane == o) {
            if (s == 0) h0 = INFD; else if (s == 1) h1 = INFD;
            else if (s == 2) h2 = INFD; else h3 = INFD;
        }
        double hm = fmin(fmin(h0, h1), fmin(h2, h3));
        unsigned long long ka = (unsigned long long)__double_as_longlong(hm);
        RED_ALL();
        double m = __longlong_as_double((long long)ka);
        if (lane == o) {
            if (s == 0)      { vj0 -= m; up0 += m; }
            else if (s == 1) { vj1 -= m; up1 += m; }
            else if (s == 2) { vj2 -= m; up2 += m; }
            else             { vj3 -= m; up3 += m; }
        }
    }

    // ================= GREEDY-2: assign free rows whose argmin column is free ==
    for (int i = 1; i <= NN; ++i) {
        unsigned long long amv = (i <= 64) ? am0 : (i <= 128) ? am1 : (i <= 192) ? am2 : am3;
        if ((amv >> ((i - 1) & 63)) & 1ULL) continue;
        float4 cr = LOAD_ROW(i);
        double du = (double)ldsU[i - 1];
        double h0 = ((double)cr.x - du) - vj0;
        double h1 = ((double)cr.y - du) - vj1;
        double h2 = ((double)cr.z - du) - vj2;
        double h3 = ((double)cr.w - du) - vj3;
        unsigned long long k0 = dkey(h0, 4 * lane + 1);
        unsigned long long k1 = dkey(h1, 4 * lane + 2);
        unsigned long long k2 = dkey(h2, 4 * lane + 3);
        unsigned long long k3 = dkey(h3, 4 * lane + 4);
        unsigned long long ea = k1 < k0 ? k1 : k0;
        unsigned long long eb = k3 < k2 ? k3 : k2;
        unsigned long long ka = eb < ea ? eb : ea;
        RED_ALL();
        int j1 = (int)(ka & 511ULL);
        int o1 = (j1 - 1) >> 2, s1 = (j1 - 1) & 3;
        int pcur = __builtin_amdgcn_readlane(SEL4I(s1, pj0_, pj1_, pj2_, pj3_), o1);
        if (pcur == 0) {                  // argmin column free -> take it
            double u_i = du + unkey(ka);
            if (lane == o1) {
                if (s1 == 0)      { pj0_ = i; up0 = u_i; }
                else if (s1 == 1) { pj1_ = i; up1 = u_i; }
                else if (s1 == 2) { pj2_ = i; up2 = u_i; }
                else              { pj3_ = i; up3 = u_i; }
            }
            unsigned long long bit = 1ULL << ((i - 1) & 63);
            if (i <= 64) am0 |= bit; else if (i <= 128) am1 |= bit;
            else if (i <= 192) am2 |= bit; else am3 |= bit;
        }
    }

    // ================= SSP (Dijkstra) for remaining free rows =================
    for (int i = 1; i <= NN; ++i) {
        unsigned long long amv = (i <= 64) ? am0 : (i <= 128) ? am1 : (i <= 192) ? am2 : am3;
        if ((amv >> ((i - 1) & 63)) & 1ULL) continue;   // row assigned

        double u_i = (double)ldsU[i - 1];   // u[i] starts at row dual
        double mv0 = INFD, mv1 = INFD, mv2 = INFD, mv3 = INFD;
        int used4 = 0;
        int j0 = 0;
        double ui0 = u_i;
        float4 cr = LOAD_ROW(i);            // current row (i0 = i)

        for (int it = 0; it <= NN; ++it) {
            double uv0 = ui0 + vj0, uv1 = ui0 + vj1, uv2 = ui0 + vj2, uv3 = ui0 + vj3;

            if (!(used4 & 1)) { double cur = (double)cr.x - uv0; if (cur < mv0) { mv0 = cur; wy0 = j0; } }
            if (!(used4 & 2)) { double cur = (double)cr.y - uv1; if (cur < mv1) { mv1 = cur; wy1 = j0; } }
            if (!(used4 & 4)) { double cur = (double)cr.z - uv2; if (cur < mv2) { mv2 = cur; wy2 = j0; } }
            if (!(used4 & 8)) { double cur = (double)cr.w - uv3; if (cur < mv3) { mv3 = cur; wy3 = j0; } }

            unsigned long long k0 = (used4 & 1) ? MAXK : dkey(mv0, 4 * lane + 1);
            unsigned long long k1 = (used4 & 2) ? MAXK : dkey(mv1, 4 * lane + 2);
            unsigned long long k2 = (used4 & 4) ? MAXK : dkey(mv2, 4 * lane + 3);
            unsigned long long k3 = (used4 & 8) ? MAXK : dkey(mv3, 4 * lane + 4);

            // local payload reduce: winner's assigned row travels with the key
            unsigned long long ka; int pa_l;
            if (k1 < k0) { ka = k1; pa_l = pj1_; } else { ka = k0; pa_l = pj0_; }
            unsigned long long kb2; int pb2;
            if (k3 < k2) { kb2 = k3; pb2 = pj3_; } else { kb2 = k2; pb2 = pj2_; }
            if (kb2 < ka) { ka = kb2; pa_l = pb2; }

            // 4 payload DPP steps: lanes 15/31/47/63 hold 16-lane-group winners
            RED_DPP_P(0x111); RED_DPP_P(0x112); RED_DPP_P(0x114); RED_DPP_P(0x118);

            // speculative prefetch: global winner is one of the 4 group winners
            int pc0 = __builtin_amdgcn_readlane(pa_l, 15);
            int pc1 = __builtin_amdgcn_readlane(pa_l, 31);
            int pc2 = __builtin_amdgcn_readlane(pa_l, 47);
            int pc3 = __builtin_amdgcn_readlane(pa_l, 63);
            float4 cc0 = LOAD_ROW(pc0 > 0 ? pc0 : 1);
            float4 cc1 = LOAD_ROW(pc1 > 0 ? pc1 : 1);
            float4 cc2 = LOAD_ROW(pc2 > 0 ? pc2 : 1);
            float4 cc3 = LOAD_ROW(pc3 > 0 ? pc3 : 1);

            // finish reduce key-only; broadcast from lane 63
            RED_DPP_K(0x142); RED_DPP_K(0x143);
            {
                unsigned int klo = (unsigned int)__builtin_amdgcn_readlane((int)(unsigned int)ka, 63);
                unsigned int khi = (unsigned int)__builtin_amdgcn_readlane((int)(unsigned int)(ka >> 32), 63);
                ka = ((unsigned long long)khi << 32) | klo;
            }

            double delta = unkey(ka);
            int j1 = (int)(ka & 511ULL);
            int o1 = (j1 - 1) >> 2, s1 = (j1 - 1) & 3;
            int g = o1 >> 4;                       // winner's 16-lane group
            int pa = (g == 0) ? pc0 : (g == 1) ? pc1 : (g == 2) ? pc2 : pc3;
            double ua = readlane_d(SEL4D(s1, up0, up1, up2, up3), o1);

            u_i += delta;
            if (used4 & 1) { up0 += delta; vj0 -= delta; } else { mv0 -= delta; }
            if (used4 & 2) { up1 += delta; vj1 -= delta; } else { mv1 -= delta; }
            if (used4 & 4) { up2 += delta; vj2 -= delta; } else { mv2 -= delta; }
            if (used4 & 8) { up3 += delta; vj3 -= delta; } else { mv3 -= delta; }

            j0 = j1;
            if (pa == 0) break;            // reached a free column
            int ci = j1 - 1;
            if ((ci >> 2) == lane) used4 |= 1 << (ci & 3);
            ui0 = ua;
            cr = (g == 0) ? cc0 : (g == 1) ? cc1 : (g == 2) ? cc2 : cc3;
        }

        // ---- augment along way pointers (all indices uniform -> readlane) ----
        int jj = j0;
        while (jj) {
            int o = (jj - 1) >> 2, s = (jj - 1) & 3;
            int wv = SEL4I(s, wy0, wy1, wy2, wy3);
            int jn = __builtin_amdgcn_readlane(wv, o);
            int pn; double un;
            if (jn == 0) { pn = i; un = u_i; }
            else {
                int o2 = (jn - 1) >> 2, s2 = (jn - 1) & 3;
                int pv = SEL4I(s2, pj0_, pj1_, pj2_, pj3_);
                double uv = SEL4D(s2, up0, up1, up2, up3);
                pn = __builtin_amdgcn_readlane(pv, o2);
                un = readlane_d(uv, o2);
            }
            if (lane == o) {
                if (s == 0)      { pj0_ = pn; up0 = un; }
                else if (s == 1) { pj1_ = pn; up1 = un; }
                else if (s == 2) { pj2_ = pn; up2 = un; }
                else             { pj3_ = pn; up3 = un; }
            }
            jj = jn;
        }
    }

    // col_of_row: cols[p[j]-1] = j-1
    cols[b * NN + (pj0_ - 1)] = 4 * lane + 0;
    cols[b * NN + (pj1_ - 1)] = 4 * lane + 1;
    cols[b * NN + (pj2_ - 1)] = 4 * lane + 2;
    cols[b * NN + (pj3_ - 1)] = 4 * lane + 3;
    #undef LOAD_ROW
}

// ---------- K4: matched losses, per-block (batch) partial sums ----------
__global__ __launch_bounds__(256) void k_loss(const float* __restrict__ lp,
                                              const float* __restrict__ bp,
                                              const float* __restrict__ lt,
                                              const float* __restrict__ bt,
                                              const int* __restrict__ cols,
                                              float* __restrict__ partials) {
    int b = blockIdx.x, n = threadIdx.x;
    int col = cols[b * NN + n];
    float x = lp[b * NN + n];
    float pp = 1.f / (1.f + expf(-x));
    float t = lt[b * MM + col];
    float4 P = *reinterpret_cast<const float4*>(bp + ((size_t)b * NN + n) * 4);
    float4 T = *reinterpret_cast<const float4*>(bt + ((size_t)b * MM + col) * 4);
    float w = (t == 1.f) ? 1.f : 0.f;
    float iou, diou;
    iou_diou(P, T, iou, diou);
    float bce = -(t * fmaxf(logf(pp), -100.f) + (1.f - t) * fmaxf(logf(1.f - pp), -100.f));
    float l1 = fabsf(P.x - T.x) + fabsf(P.y - T.y) + fabsf(P.z - T.z) + fabsf(P.w - T.w);

    float v0 = w, v1 = diou * w, v2 = iou * w, v3 = bce, v4 = l1 * w;
    #pragma unroll
    for (int mm = 1; mm < 64; mm <<= 1) {
        v0 += __shfl_xor(v0, mm); v1 += __shfl_xor(v1, mm);
        v2 += __shfl_xor(v2, mm); v3 += __shfl_xor(v3, mm);
        v4 += __shfl_xor(v4, mm);
    }
    __shared__ float red[4][5];
    int wid = n >> 6, lane = n & 63;
    if (lane == 0) { red[wid][0] = v0; red[wid][1] = v1; red[wid][2] = v2; red[wid][3] = v3; red[wid][4] = v4; }
    __syncthreads();
    if (n == 0) {
        float s0 = red[0][0] + red[1][0] + red[2][0] + red[3][0];
        float s1 = red[0][1] + red[1][1] + red[2][1] + red[3][1];
        float s2 = red[0][2] + red[1][2] + red[2][2] + red[3][2];
        float s3 = red[0][3] + red[1][3] + red[2][3] + red[3][3];
        float s4 = red[0][4] + red[1][4] + red[2][4] + red[3][4];
        partials[b * 8 + 0] = s0; partials[b * 8 + 1] = s1; partials[b * 8 + 2] = s2;
        partials[b * 8 + 3] = s3; partials[b * 8 + 4] = s4;
    }
}

// ---------- K5: final scalar combine ----------
__global__ __launch_bounds__(64) void k_final(const float* __restrict__ partials,
                                              float* __restrict__ out) {
    int t = threadIdx.x;
    float v0 = partials[t * 8 + 0], v1 = partials[t * 8 + 1], v2 = partials[t * 8 + 2];
    float v3 = partials[t * 8 + 3], v4 = partials[t * 8 + 4];
    #pragma unroll
    for (int mm = 1; mm < 64; mm <<= 1) {
        v0 += __shfl_xor(v0, mm); v1 += __shfl_xor(v1, mm);
        v2 += __shfl_xor(v2, mm); v3 += __shfl_xor(v3, mm);
        v4 += __shfl_xor(v4, mm);
    }
    if (t == 0) {
        float wsum = v0;
        float diou_loss = v1 / wsum;
        float iou = v2 / wsum;
        float label_loss = v3 * (1.f / (64.f * 256.f));
        float bbox_loss = v4 / (wsum * 4.f);
        out[0] = diou_loss + label_loss + bbox_loss;
        out[1] = iou;
    }
}

extern "C" void kernel_launch(void* const* d_in, const int* in_sizes, int n_in,
                              void* d_out, int out_size, void* d_ws, size_t ws_size,
                              hipStream_t stream) {
    const float* labels_pred   = (const float*)d_in[0];
    const float* bbox_pred     = (const float*)d_in[1];
    const float* labels_target = (const float*)d_in[2];
    const float* bbox_target   = (const float*)d_in[3];
    float* out = (float*)d_out;

    float* A    = (float*)d_ws;
    float* C    = A + BB * NN;
    float* lc   = C + BB * NN;
    float* l1c  = lc + NN * MM;
    float* cost = l1c + NN * MM;
    int*   cols = (int*)(cost + (size_t)BB * NN * MM);
    float* partials = (float*)(cols + BB * NN);

    k_prep<<<BB * NN / 256, 256, 0, stream>>>(labels_pred, A, C);
    k_nm<<<NN, MM, 0, stream>>>(A, C, bbox_pred, bbox_target, labels_target, lc, l1c);
    k_cost<<<BB * NN, MM, 0, stream>>>(bbox_pred, bbox_target, lc, l1c, cost);
    k_hungarian<<<BB, 64, 0, stream>>>(cost, cols);
    k_loss<<<BB, NN, 0, stream>>>(labels_pred, bbox_pred, labels_target, bbox_target, cols, partials);
    k_final<<<1, 64, 0, stream>>>(partials, out);
}

// Round 10
// 2451.790 us; speedup vs baseline: 1.1098x; 1.1098x over previous
//
#include <hip/hip_runtime.h>
#include <math.h>

#define BB 64
#define NN 256
#define MM 256
#define EPSF 1e-7f
#define ROWS_LDS 156   // 156 KB row cache + jofrow/matches/u0 ~3 KB = 159 KB <= 160 KB

// ---------- helpers ----------

__device__ __forceinline__ void iou_diou(const float4 pb, const float4 tb,
                                         float& iou, float& diou) {
    float x1 = pb.x - pb.z * 0.5f, y1 = pb.y - pb.w * 0.5f;
    float x2 = pb.x + pb.z * 0.5f, y2 = pb.y + pb.w * 0.5f;
    float xg1 = tb.x - tb.z * 0.5f, yg1 = tb.y - tb.w * 0.5f;
    float xg2 = tb.x + tb.z * 0.5f, yg2 = tb.y + tb.w * 0.5f;
    float xi1 = fmaxf(x1, xg1), yi1 = fmaxf(y1, yg1);
    float xi2 = fminf(x2, xg2), yi2 = fminf(y2, yg2);
    float inter = fmaxf(xi2 - xi1, 0.f) * fmaxf(yi2 - yi1, 0.f);
    float uni = (x2 - x1) * (y2 - y1) + (xg2 - xg1) * (yg2 - yg1) - inter;
    iou = inter / uni;
    float iou_e = inter / (uni + EPSF);
    float xc1 = fminf(x1, xg1), yc1 = fminf(y1, yg1);
    float xc2 = fmaxf(x2, xg2), yc2 = fmaxf(y2, yg2);
    float dx = xc2 - xc1, dy = yc2 - yc1;
    float diag = dx * dx + dy * dy + EPSF;
    float ex = (x1 + x2 - xg1 - xg2) * 0.5f;
    float ey = (y1 + y2 - yg1 - yg2) * 0.5f;
    float dist = ex * ex + ey * ey;
    diou = 1.f - iou_e + dist / diag;
}

// monotone double -> u64 key, low 9 bits replaced by column index (1..256).
__device__ __forceinline__ unsigned long long dkey(double d, int j) {
    unsigned long long b = (unsigned long long)__double_as_longlong(d);
    b ^= (b >> 63) ? 0xFFFFFFFFFFFFFFFFULL : 0x8000000000000000ULL;
    return (b & ~511ULL) | (unsigned long long)j;
}
__device__ __forceinline__ double unkey(unsigned long long k) {
    unsigned long long b = k & ~511ULL;
    b ^= (b & 0x8000000000000000ULL) ? 0x8000000000000000ULL : 0xFFFFFFFFFFFFFFFFULL;
    return __longlong_as_double((long long)b);
}

#define SEL4I(s, a0, a1, a2, a3) ((s) == 0 ? (a0) : (s) == 1 ? (a1) : (s) == 2 ? (a2) : (a3))
#define SEL4D(s, a0, a1, a2, a3) ((s) == 0 ? (a0) : (s) == 1 ? (a1) : (s) == 2 ? (a2) : (a3))

// uniform-lane readlane of a double held in a VGPR pair
__device__ __forceinline__ double readlane_d(double v, int lane) {
    unsigned long long b = (unsigned long long)__double_as_longlong(v);
    int lo = __builtin_amdgcn_readlane((int)(unsigned int)b, lane);
    int hi = __builtin_amdgcn_readlane((int)(unsigned int)(b >> 32), lane);
    return __longlong_as_double((long long)(((unsigned long long)(unsigned int)hi << 32) |
                                            (unsigned long long)(unsigned int)lo));
}

// Directional DPP min-reduce step, KEY ONLY (u64). old=self, bound_ctrl=false.
// Sequence row_shr:1,2,4,8 then row_bcast:15, row_bcast:31 -> lane 63 = min.
#define RED_DPP_K(CTRL)                                                                     \
    do {                                                                                    \
        int lo_ = (int)(unsigned int)ka, hi_ = (int)(unsigned int)(ka >> 32);               \
        int nlo_ = __builtin_amdgcn_update_dpp(lo_, lo_, CTRL, 0xF, 0xF, false);            \
        int nhi_ = __builtin_amdgcn_update_dpp(hi_, hi_, CTRL, 0xF, 0xF, false);            \
        unsigned long long ok_ = ((unsigned long long)(unsigned int)nhi_ << 32) |           \
                                 (unsigned long long)(unsigned int)nlo_;                    \
        if (ok_ < ka) ka = ok_;                                                             \
    } while (0)

#define RED_ALL()                                                                           \
    do {                                                                                    \
        RED_DPP_K(0x111); RED_DPP_K(0x112); RED_DPP_K(0x114); RED_DPP_K(0x118);             \
        RED_DPP_K(0x142); RED_DPP_K(0x143);                                                 \
        unsigned int klo_ = (unsigned int)__builtin_amdgcn_readlane((int)(unsigned int)ka, 63); \
        unsigned int khi_ = (unsigned int)__builtin_amdgcn_readlane((int)(unsigned int)(ka >> 32), 63); \
        ka = ((unsigned long long)khi_ << 32) | klo_;                                       \
    } while (0)

// u32 min reduce (for nonneg f32 bits — monotone). Result broadcast from lane 63.
#define RED_U32_STEP(CTRL)                                                                  \
    do {                                                                                    \
        unsigned int n_ = (unsigned int)__builtin_amdgcn_update_dpp((int)kb, (int)kb, CTRL, 0xF, 0xF, false); \
        if (n_ < kb) kb = n_;                                                               \
    } while (0)
#define RED_U32_ALL()                                                                       \
    do {                                                                                    \
        RED_U32_STEP(0x111); RED_U32_STEP(0x112); RED_U32_STEP(0x114); RED_U32_STEP(0x118); \
        RED_U32_STEP(0x142); RED_U32_STEP(0x143);                                           \
        kb = (unsigned int)__builtin_amdgcn_readlane((int)kb, 63);                          \
    } while (0)

// ---------- K0: per-(b,n) BCE log terms ----------
__global__ __launch_bounds__(256) void k_prep(const float* __restrict__ lp,
                                              float* __restrict__ A,
                                              float* __restrict__ C) {
    int idx = blockIdx.x * 256 + threadIdx.x;
    float x = lp[idx];
    float p = 1.f / (1.f + expf(-x));
    A[idx] = -fmaxf(logf(p), -100.f);
    C[idx] = -fmaxf(logf(1.f - p), -100.f);
}

// ---------- K1: batch-constant label_cost and l1_cost [N,M] ----------
__global__ __launch_bounds__(256) void k_nm(const float* __restrict__ A,
                                            const float* __restrict__ C,
                                            const float* __restrict__ bp,
                                            const float* __restrict__ bt,
                                            const float* __restrict__ lt,
                                            float* __restrict__ lc,
                                            float* __restrict__ l1c) {
    int n = blockIdx.x, m = threadIdx.x;
    float sl = 0.f, s1 = 0.f;
    for (int b = 0; b < BB; ++b) {
        float a = A[b * NN + n];
        float c = C[b * NN + n];
        float t = lt[b * MM + m];
        sl += t * a + (1.f - t) * c;
        float4 P = *reinterpret_cast<const float4*>(bp + ((size_t)b * NN + n) * 4);
        float4 T = *reinterpret_cast<const float4*>(bt + ((size_t)b * MM + m) * 4);
        s1 += fabsf(P.x - T.x) + fabsf(P.y - T.y) + fabsf(P.z - T.z) + fabsf(P.w - T.w);
    }
    lc[n * MM + m]  = sl * (1.f / 64.f);
    l1c[n * MM + m] = s1 * (1.f / 256.f);
}

// ---------- K2: full cost tensor [B,N,M] ----------
__global__ __launch_bounds__(256) void k_cost(const float* __restrict__ bp,
                                              const float* __restrict__ bt,
                                              const float* __restrict__ lc,
                                              const float* __restrict__ l1c,
                                              float* __restrict__ cost) {
    int bn = blockIdx.x;
    int b = bn >> 8, n = bn & 255;
    int m = threadIdx.x;
    float4 P = *reinterpret_cast<const float4*>(bp + ((size_t)bn) * 4);
    float4 T = *reinterpret_cast<const float4*>(bt + ((size_t)b * MM + m) * 4);
    float iou, diou;
    iou_diou(P, T, iou, diou);
    cost[((size_t)bn << 8) + m] = diou + lc[(n << 8) + m] + l1c[(n << 8) + m];
}

// ---------- K3: exact LAP (rowred + colred + RT + greedy2 + SSP), 1 wave/batch --
__global__ __launch_bounds__(64) void k_hungarian(const float* __restrict__ cost,
                                                  int* __restrict__ cols) {
    const int b = blockIdx.x;
    const int lane = threadIdx.x;
    const float* Cm = cost + (size_t)b * NN * MM;
    const unsigned long long MAXK = 0xFFFFFFFFFFFFFFFFULL;
    const double INFD = __builtin_inf();

    __shared__ float ldsC[ROWS_LDS * MM];
    __shared__ float ldsU[NN];       // row duals u0[i] (exact f32 row minima)
    __shared__ int jofrow[NN + 1];   // smallest column (1-based) whose argmin is this row
    __shared__ int matches[NN + 1];  // # columns whose argmin is this row
    for (int r = lane; r <= NN; r += 64) { jofrow[r] = 0x7fffffff; matches[r] = 0; }
    __syncthreads();

    // ---- fused row reduction + column reduction on (c - u0) + LDS stash ----
    // u0[i] = min_j c[i][j] (exact f32); cm[j] = min_i ((double)c - (double)u0[i])
    // (each diff is exact in f64 since both operands are f32-representable).
    double cm0 = INFD, cm1 = INFD, cm2 = INFD, cm3 = INFD;
    int rm0 = 0, rm1 = 0, rm2 = 0, rm3 = 0;
    for (int i = 0; i < NN; ++i) {
        float4 cr = *reinterpret_cast<const float4*>(Cm + (size_t)i * MM + 4 * lane);
        if (i < ROWS_LDS) *reinterpret_cast<float4*>(&ldsC[i * MM + 4 * lane]) = cr;
        // row min (all costs >= 0 -> f32 bits monotone as u32)
        float rl = fminf(fminf(cr.x, cr.y), fminf(cr.z, cr.w));
        unsigned int kb = __float_as_uint(rl);
        RED_U32_ALL();
        float u0i = __uint_as_float(kb);
        if (lane == 0) ldsU[i] = u0i;
        double du = (double)u0i;
        double h0 = (double)cr.x - du;
        double h1 = (double)cr.y - du;
        double h2 = (double)cr.z - du;
        double h3 = (double)cr.w - du;
        if (h0 < cm0) { cm0 = h0; rm0 = i; }
        if (h1 < cm1) { cm1 = h1; rm1 = i; }
        if (h2 < cm2) { cm2 = h2; rm2 = i; }
        if (h3 < cm3) { cm3 = h3; rm3 = i; }
    }
    atomicMin(&jofrow[rm0 + 1], 4 * lane + 1);
    atomicMin(&jofrow[rm1 + 1], 4 * lane + 2);
    atomicMin(&jofrow[rm2 + 1], 4 * lane + 3);
    atomicMin(&jofrow[rm3 + 1], 4 * lane + 4);
    atomicAdd(&matches[rm0 + 1], 1);
    atomicAdd(&matches[rm1 + 1], 1);
    atomicAdd(&matches[rm2 + 1], 1);
    atomicAdd(&matches[rm3 + 1], 1);
    __syncthreads();

    // ---- greedy pre-assignment + register state init ----
    double vj0 = cm0, vj1 = cm1, vj2 = cm2, vj3 = cm3;   // v[j]
    int pj0_ = (jofrow[rm0 + 1] == 4 * lane + 1) ? rm0 + 1 : 0;
    int pj1_ = (jofrow[rm1 + 1] == 4 * lane + 2) ? rm1 + 1 : 0;
    int pj2_ = (jofrow[rm2 + 1] == 4 * lane + 3) ? rm2 + 1 : 0;
    int pj3_ = (jofrow[rm3 + 1] == 4 * lane + 4) ? rm3 + 1 : 0;
    // u[p[j]] = u0[claimed row] (CS equality: u0 + v = c at the argmin)
    double up0 = pj0_ ? (double)ldsU[pj0_ - 1] : 0.0;
    double up1 = pj1_ ? (double)ldsU[pj1_ - 1] : 0.0;
    double up2 = pj2_ ? (double)ldsU[pj2_ - 1] : 0.0;
    double up3 = pj3_ ? (double)ldsU[pj3_ - 1] : 0.0;
    int wy0 = 0, wy1 = 0, wy2 = 0, wy3 = 0;              // way[j]

    // assigned-row bitmasks (wave-uniform)
    unsigned long long am0 = __ballot(jofrow[1 + lane]       != 0x7fffffff);
    unsigned long long am1 = __ballot(jofrow[1 + 64 + lane]  != 0x7fffffff);
    unsigned long long am2 = __ballot(jofrow[1 + 128 + lane] != 0x7fffffff);
    unsigned long long am3 = __ballot(jofrow[1 + 192 + lane] != 0x7fffffff);

    // ================= REDUCTION TRANSFER (rows claimed exactly once) =========
    for (int i = 1; i <= NN; ++i) {
        if (matches[i] != 1) continue;               // uniform branch
        int j1 = jofrow[i];                          // uniform
        int o = (j1 - 1) >> 2, s = (j1 - 1) & 3;
        float4 cr;
        if (i - 1 < ROWS_LDS)
            cr = *reinterpret_cast<const float4*>(&ldsC[(i - 1) * MM + 4 * lane]);
        else
            cr = *reinterpret_cast<const float4*>(Cm + (size_t)(i - 1) * MM + 4 * lane);
        double du = (double)ldsU[i - 1];
        double h0 = ((double)cr.x - du) - vj0;
        double h1 = ((double)cr.y - du) - vj1;
        double h2 = ((double)cr.z - du) - vj2;
        double h3 = ((double)cr.w - du) - vj3;
        if (lane == o) {
            if (s == 0) h0 = INFD; else if (s == 1) h1 = INFD;
            else if (s == 2) h2 = INFD; else h3 = INFD;
        }
        // all h >= 0: raw IEEE bits are monotone as u64 — exact min, no index
        double hm = fmin(fmin(h0, h1), fmin(h2, h3));
        unsigned long long ka = (unsigned long long)__double_as_longlong(hm);
        RED_ALL();
        double m = __longlong_as_double((long long)ka);
        if (lane == o) {
            if (s == 0)      { vj0 -= m; up0 += m; }
            else if (s == 1) { vj1 -= m; up1 += m; }
            else if (s == 2) { vj2 -= m; up2 += m; }
            else             { vj3 -= m; up3 += m; }
        }
    }

    // ================= GREEDY-2: assign free rows whose argmin column is free ==
    for (int i = 1; i <= NN; ++i) {
        unsigned long long amv = (i <= 64) ? am0 : (i <= 128) ? am1 : (i <= 192) ? am2 : am3;
        if ((amv >> ((i - 1) & 63)) & 1ULL) continue;
        float4 cr;
        if (i - 1 < ROWS_LDS)
            cr = *reinterpret_cast<const float4*>(&ldsC[(i - 1) * MM + 4 * lane]);
        else
            cr = *reinterpret_cast<const float4*>(Cm + (size_t)(i - 1) * MM + 4 * lane);
        double du = (double)ldsU[i - 1];
        double h0 = ((double)cr.x - du) - vj0;
        double h1 = ((double)cr.y - du) - vj1;
        double h2 = ((double)cr.z - du) - vj2;
        double h3 = ((double)cr.w - du) - vj3;
        unsigned long long k0 = dkey(h0, 4 * lane + 1);
        unsigned long long k1 = dkey(h1, 4 * lane + 2);
        unsigned long long k2 = dkey(h2, 4 * lane + 3);
        unsigned long long k3 = dkey(h3, 4 * lane + 4);
        unsigned long long ea = k1 < k0 ? k1 : k0;
        unsigned long long eb = k3 < k2 ? k3 : k2;
        unsigned long long ka = eb < ea ? eb : ea;
        RED_ALL();
        int j1 = (int)(ka & 511ULL);
        int o1 = (j1 - 1) >> 2, s1 = (j1 - 1) & 3;
        int pcur = __builtin_amdgcn_readlane(SEL4I(s1, pj0_, pj1_, pj2_, pj3_), o1);
        if (pcur == 0) {                  // argmin column free -> take it
            double u_i = du + unkey(ka);  // u[i] = u0[i] + rowmin of reduced cost
            if (lane == o1) {
                if (s1 == 0)      { pj0_ = i; up0 = u_i; }
                else if (s1 == 1) { pj1_ = i; up1 = u_i; }
                else if (s1 == 2) { pj2_ = i; up2 = u_i; }
                else              { pj3_ = i; up3 = u_i; }
            }
            unsigned long long bit = 1ULL << ((i - 1) & 63);
            if (i <= 64) am0 |= bit; else if (i <= 128) am1 |= bit;
            else if (i <= 192) am2 |= bit; else am3 |= bit;
        }
    }

    // ================= SSP (Dijkstra) for remaining free rows =================
    for (int i = 1; i <= NN; ++i) {
        unsigned long long amv = (i <= 64) ? am0 : (i <= 128) ? am1 : (i <= 192) ? am2 : am3;
        if ((amv >> ((i - 1) & 63)) & 1ULL) continue;   // row assigned

        double u_i = (double)ldsU[i - 1];   // u[i] starts at row dual
        double mv0 = INFD, mv1 = INFD, mv2 = INFD, mv3 = INFD;
        int used4 = 0;
        int j0 = 0;
        int i0 = i;
        double ui0 = u_i;

        for (int it = 0; it <= NN; ++it) {
            // off-critical-path: fold ui0 into v (1 sub on the load chain)
            double uv0 = ui0 + vj0, uv1 = ui0 + vj1, uv2 = ui0 + vj2, uv3 = ui0 + vj3;
            float4 cr;
            if (i0 - 1 < ROWS_LDS)    // wave-uniform branch
                cr = *reinterpret_cast<const float4*>(&ldsC[(i0 - 1) * MM + 4 * lane]);
            else
                cr = *reinterpret_cast<const float4*>(Cm + (size_t)(i0 - 1) * MM + 4 * lane);

            if (!(used4 & 1)) { double cur = (double)cr.x - uv0; if (cur < mv0) { mv0 = cur; wy0 = j0; } }
            if (!(used4 & 2)) { double cur = (double)cr.y - uv1; if (cur < mv1) { mv1 = cur; wy1 = j0; } }
            if (!(used4 & 4)) { double cur = (double)cr.z - uv2; if (cur < mv2) { mv2 = cur; wy2 = j0; } }
            if (!(used4 & 8)) { double cur = (double)cr.w - uv3; if (cur < mv3) { mv3 = cur; wy3 = j0; } }

            unsigned long long k0 = (used4 & 1) ? MAXK : dkey(mv0, 4 * lane + 1);
            unsigned long long k1 = (used4 & 2) ? MAXK : dkey(mv1, 4 * lane + 2);
            unsigned long long k2 = (used4 & 4) ? MAXK : dkey(mv2, 4 * lane + 3);
            unsigned long long k3 = (used4 & 8) ? MAXK : dkey(mv3, 4 * lane + 4);

            unsigned long long ea = k1 < k0 ? k1 : k0;
            unsigned long long eb = k3 < k2 ? k3 : k2;
            unsigned long long ka = eb < ea ? eb : ea;

            // key-only DPP reduce (no payload), winner broadcast from lane 63
            RED_ALL();

            double delta = unkey(ka);
            int j1 = (int)(ka & 511ULL);
            int o1 = (j1 - 1) >> 2, s1 = (j1 - 1) & 3;
            // post-reduce uniform-lane fetches (SALU-side, no LDS pipe)
            int pa = __builtin_amdgcn_readlane(SEL4I(s1, pj0_, pj1_, pj2_, pj3_), o1);
            double ua = readlane_d(SEL4D(s1, up0, up1, up2, up3), o1);

            u_i += delta;
            if (used4 & 1) { up0 += delta; vj0 -= delta; } else { mv0 -= delta; }
            if (used4 & 2) { up1 += delta; vj1 -= delta; } else { mv1 -= delta; }
            if (used4 & 4) { up2 += delta; vj2 -= delta; } else { mv2 -= delta; }
            if (used4 & 8) { up3 += delta; vj3 -= delta; } else { mv3 -= delta; }

            j0 = j1;
            if (pa == 0) break;            // reached a free column
            int ci = j1 - 1;
            if ((ci >> 2) == lane) used4 |= 1 << (ci & 3);
            i0 = pa;
            ui0 = ua;
        }

        // ---- augment along way pointers (all indices uniform -> readlane) ----
        int jj = j0;
        while (jj) {
            int o = (jj - 1) >> 2, s = (jj - 1) & 3;
            int wv = SEL4I(s, wy0, wy1, wy2, wy3);
            int jn = __builtin_amdgcn_readlane(wv, o);
            int pn; double un;
            if (jn == 0) { pn = i; un = u_i; }
            else {
                int o2 = (jn - 1) >> 2, s2 = (jn - 1) & 3;
                int pv = SEL4I(s2, pj0_, pj1_, pj2_, pj3_);
                double uv = SEL4D(s2, up0, up1, up2, up3);
                pn = __builtin_amdgcn_readlane(pv, o2);
                un = readlane_d(uv, o2);
            }
            if (lane == o) {
                if (s == 0)      { pj0_ = pn; up0 = un; }
                else if (s == 1) { pj1_ = pn; up1 = un; }
                else if (s == 2) { pj2_ = pn; up2 = un; }
                else             { pj3_ = pn; up3 = un; }
            }
            jj = jn;
        }
    }

    // col_of_row: cols[p[j]-1] = j-1
    cols[b * NN + (pj0_ - 1)] = 4 * lane + 0;
    cols[b * NN + (pj1_ - 1)] = 4 * lane + 1;
    cols[b * NN + (pj2_ - 1)] = 4 * lane + 2;
    cols[b * NN + (pj3_ - 1)] = 4 * lane + 3;
}

// ---------- K4: matched losses, per-block (batch) partial sums ----------
__global__ __launch_bounds__(256) void k_loss(const float* __restrict__ lp,
                                              const float* __restrict__ bp,
                                              const float* __restrict__ lt,
                                              const float* __restrict__ bt,
                                              const int* __restrict__ cols,
                                              float* __restrict__ partials) {
    int b = blockIdx.x, n = threadIdx.x;
    int col = cols[b * NN + n];
    float x = lp[b * NN + n];
    float pp = 1.f / (1.f + expf(-x));
    float t = lt[b * MM + col];
    float4 P = *reinterpret_cast<const float4*>(bp + ((size_t)b * NN + n) * 4);
    float4 T = *reinterpret_cast<const float4*>(bt + ((size_t)b * MM + col) * 4);
    float w = (t == 1.f) ? 1.f : 0.f;
    float iou, diou;
    iou_diou(P, T, iou, diou);
    float bce = -(t * fmaxf(logf(pp), -100.f) + (1.f - t) * fmaxf(logf(1.f - pp), -100.f));
    float l1 = fabsf(P.x - T.x) + fabsf(P.y - T.y) + fabsf(P.z - T.z) + fabsf(P.w - T.w);

    float v0 = w, v1 = diou * w, v2 = iou * w, v3 = bce, v4 = l1 * w;
    #pragma unroll
    for (int mm = 1; mm < 64; mm <<= 1) {
        v0 += __shfl_xor(v0, mm); v1 += __shfl_xor(v1, mm);
        v2 += __shfl_xor(v2, mm); v3 += __shfl_xor(v3, mm);
        v4 += __shfl_xor(v4, mm);
    }
    __shared__ float red[4][5];
    int wid = n >> 6, lane = n & 63;
    if (lane == 0) { red[wid][0] = v0; red[wid][1] = v1; red[wid][2] = v2; red[wid][3] = v3; red[wid][4] = v4; }
    __syncthreads();
    if (n == 0) {
        float s0 = red[0][0] + red[1][0] + red[2][0] + red[3][0];
        float s1 = red[0][1] + red[1][1] + red[2][1] + red[3][1];
        float s2 = red[0][2] + red[1][2] + red[2][2] + red[3][2];
        float s3 = red[0][3] + red[1][3] + red[2][3] + red[3][3];
        float s4 = red[0][4] + red[1][4] + red[2][4] + red[3][4];
        partials[b * 8 + 0] = s0; partials[b * 8 + 1] = s1; partials[b * 8 + 2] = s2;
        partials[b * 8 + 3] = s3; partials[b * 8 + 4] = s4;
    }
}

// ---------- K5: final scalar combine ----------
__global__ __launch_bounds__(64) void k_final(const float* __restrict__ partials,
                                              float* __restrict__ out) {
    int t = threadIdx.x;
    float v0 = partials[t * 8 + 0], v1 = partials[t * 8 + 1], v2 = partials[t * 8 + 2];
    float v3 = partials[t * 8 + 3], v4 = partials[t * 8 + 4];
    #pragma unroll
    for (int mm = 1; mm < 64; mm <<= 1) {
        v0 += __shfl_xor(v0, mm); v1 += __shfl_xor(v1, mm);
        v2 += __shfl_xor(v2, mm); v3 += __shfl_xor(v3, mm);
        v4 += __shfl_xor(v4, mm);
    }
    if (t == 0) {
        float wsum = v0;
        float diou_loss = v1 / wsum;
        float iou = v2 / wsum;
        float label_loss = v3 * (1.f / (64.f * 256.f));
        float bbox_loss = v4 / (wsum * 4.f);
        out[0] = diou_loss + label_loss + bbox_loss;
        out[1] = iou;
    }
}

extern "C" void kernel_launch(void* const* d_in, const int* in_sizes, int n_in,
                              void* d_out, int out_size, void* d_ws, size_t ws_size,
                              hipStream_t stream) {
    const float* labels_pred   = (const float*)d_in[0];
    const float* bbox_pred     = (const float*)d_in[1];
    const float* labels_target = (const float*)d_in[2];
    const float* bbox_target   = (const float*)d_in[3];
    float* out = (float*)d_out;

    float* A    = (float*)d_ws;
    float* C    = A + BB * NN;
    float* lc   = C + BB * NN;
    float* l1c  = lc + NN * MM;
    float* cost = l1c + NN * MM;
    int*   cols = (int*)(cost + (size_t)BB * NN * MM);
    float* partials = (float*)(cols + BB * NN);

    k_prep<<<BB * NN / 256, 256, 0, stream>>>(labels_pred, A, C);
    k_nm<<<NN, MM, 0, stream>>>(A, C, bbox_pred, bbox_target, labels_target, lc, l1c);
    k_cost<<<BB * NN, MM, 0, stream>>>(bbox_pred, bbox_target, lc, l1c, cost);
    k_hungarian<<<BB, 64, 0, stream>>>(cost, cols);
    k_loss<<<BB, NN, 0, stream>>>(labels_pred, bbox_pred, labels_target, bbox_target, cols, partials);
    k_final<<<1, 64, 0, stream>>>(partials, out);
}